// Round 10
// baseline (331.201 us; speedup 1.0000x reference)
//
#include <hip/hip_runtime.h>

#define DEV __device__ __forceinline__
#define SB0 __builtin_amdgcn_sched_barrier(0)

typedef unsigned short u16;
typedef __attribute__((ext_vector_type(4))) float f32x4;
typedef __attribute__((ext_vector_type(8))) short short8;

DEV u16 f2bf(float f) {
  union { float f; unsigned u; } c; c.f = f;
  unsigned u = c.u;
  unsigned r = (u + 0x7FFFu + ((u >> 16) & 1u)) >> 16;
  return (u16)r;
}
DEV float bf2f(u16 h) {
  union { unsigned u; float f; } c; c.u = ((unsigned)h) << 16;
  return c.f;
}
DEV unsigned cvtpk(float a, float b) {
  unsigned r;
  asm("v_cvt_pk_bf16_f32 %0, %1, %2" : "=v"(r) : "v"(a), "v"(b));
  return r;
}

DEV void gload16(const void* g, void* l) {
  __builtin_amdgcn_global_load_lds(
      (__attribute__((address_space(1))) void*)(g),
      (__attribute__((address_space(3))) void*)(l), 16, 0, 0);
}
template <int N> DEV void vmcw() {
  if constexpr (N == 0) asm volatile("s_waitcnt vmcnt(0)" ::: "memory");
  else if constexpr (N == 8) asm volatile("s_waitcnt vmcnt(8)" ::: "memory");
  SB0;
}
DEV void lgkm0() { asm volatile("s_waitcnt lgkmcnt(0)" ::: "memory"); SB0; }

// ---------- merged prep: cast src->bf16 + 5 weight transposes ----------
__global__ __launch_bounds__(256) void prep_kernel(
    const float* __restrict__ src, const float* __restrict__ q_w,
    const float* __restrict__ kv_w, const float* __restrict__ out_w,
    const float* __restrict__ w1, const float* __restrict__ w2,
    u16* __restrict__ Xbf, u16* __restrict__ WqkvT, u16* __restrict__ WoT,
    u16* __restrict__ W1T, u16* __restrict__ W2T) {
  __shared__ float tile[32 * 33];
  int bb = blockIdx.x, tid = threadIdx.x;
  if (bb < 4096) {
    int i = bb * 256 + tid;
    float4 v = reinterpret_cast<const float4*>(src)[i];
    ushort4 o;
    o.x = f2bf(v.x); o.y = f2bf(v.y); o.z = f2bf(v.z); o.w = f2bf(v.w);
    reinterpret_cast<ushort4*>(Xbf)[i] = o;
    return;
  }
  const float* in; u16* outp; int ld_in, ld_out, bx, by;
  if (bb < 5120)       { int t = bb - 4096;  in = q_w;   outp = WqkvT; ld_in = 1024; ld_out = 1024; bx = t & 31;  by = t >> 5; }
  else if (bb < 7168)  { int t = bb - 5120;  in = kv_w;  outp = WqkvT + (size_t)1024 * 1024; ld_in = 2048; ld_out = 1024; bx = t & 63;  by = t >> 6; }
  else if (bb < 8192)  { int t = bb - 7168;  in = out_w; outp = WoT;   ld_in = 1024; ld_out = 1024; bx = t & 31;  by = t >> 5; }
  else if (bb < 12288) { int t = bb - 8192;  in = w1;    outp = W1T;   ld_in = 4096; ld_out = 1024; bx = t & 127; by = t >> 7; }
  else                 { int t = bb - 12288; in = w2;    outp = W2T;   ld_in = 1024; ld_out = 4096; bx = t & 31;  by = t >> 5; }
  int tx = tid & 31, ty = tid >> 5;
  int c0 = bx * 32, r0 = by * 32;
#pragma unroll
  for (int j = 0; j < 4; ++j)
    tile[(ty + j * 8) * 33 + tx] = in[(size_t)(r0 + ty + j * 8) * ld_in + c0 + tx];
  __syncthreads();
#pragma unroll
  for (int j = 0; j < 4; ++j)
    outp[(size_t)(c0 + ty + j * 8) * ld_out + r0 + tx] = f2bf(tile[tx * 33 + ty + j * 8]);
}

// ---------- Vtp extraction (key-permuted V^T; see R4 notes) ----------
__global__ __launch_bounds__(256) void transpose_vtp_kernel(
    const u16* __restrict__ in, u16* __restrict__ out) {
  __shared__ float tile[32][33];
  int c0 = blockIdx.x * 32, r0 = blockIdx.y * 32;
  int tx = threadIdx.x, ty = threadIdx.y;
#pragma unroll
  for (int j = 0; j < 4; ++j)
    tile[ty + j * 8][tx] = bf2f(in[(size_t)(r0 + ty + j * 8) * 3072 + 2048 + c0 + tx]);
  __syncthreads();
  int k = r0 + tx;
  int base = k & ~63, kb = k & 63;
  int n = kb >> 4, w = kb & 15;
  int p = ((n >> 1) << 5) | ((w >> 2) << 3) | ((n & 1) << 2) | (w & 3);
#pragma unroll
  for (int j = 0; j < 4; ++j)
    out[(size_t)(c0 + ty + j * 8) * 4096 + base + p] = f2bf(tile[tx][ty + j * 8]);
}

// ---------- 4-phase 256x256 ring-4 GEMM, 8 waves (2M x 4N) ----------
// Ring invariants identical to the proven ring kernel (stage slot = read
// slot + 3 mod 4; one counted vmcnt(8) per K-step). New: the K-step is split
// into 4 sub-phases, each {2 ds_read A (+4 B in ph0), 1 gload16 stage round,
// s_barrier, lgkmcnt(0), setprio(1), 8 MFMA, setprio(0), s_barrier} so loads
// and MFMA of co-resident waves interleave (m201-style schedule).
template <typename OutT, bool RELU>
__global__ __launch_bounds__(512, 2) void gemm_4ph_kernel(
    const u16* __restrict__ A, int lda,
    const u16* __restrict__ Bt, int ldb,
    const float* __restrict__ bias, const float* __restrict__ bias2, int split,
    OutT* __restrict__ C, int ldc, size_t c_off, int K, float scale) {
  constexpr int BM = 256, RING = 4, DEPTH = 3;
  constexpr int SLOT = 512 * 32;  // (BM+BN)*32 u16 = 32KB
  __shared__ __align__(16) u16 ring[RING][SLOT];

  const int tid = threadIdx.x;
  const int lane = tid & 63, wid = tid >> 6;
  const int wr = wid >> 2, wc = wid & 3;
  const int lr = lane & 15, hi = lane >> 4;
  const int z = blockIdx.z;

  const int gx = gridDim.x;
  const int nwg = gx * gridDim.y;
  const int orig = blockIdx.y * gx + blockIdx.x;
  const int q8 = nwg >> 3, r8 = nwg & 7, xcd = orig & 7, oo = orig >> 3;
  const int lid = (xcd < r8 ? xcd * (q8 + 1) : r8 * (q8 + 1) + (xcd - r8) * q8) + oo;
  const int rb = lid / gx, cb = lid % gx;

  const u16* Abase = A + (size_t)rb * BM * lda + (size_t)z * K;
  const u16* Bbase = Bt + (size_t)cb * BM * ldb + (size_t)z * K;
  C += (size_t)z * c_off;

  auto stage1 = [&](int slot, int kt, int j) {
    int u = wid * 4 + j;                 // 16-row unit in A|B concat (0..31)
    int rloc = u * 16 + (lane >> 2);
    int cs = (lane & 3) ^ ((rloc >> 1) & 3);
    const u16* src;
    if (u < 16) src = Abase + (size_t)rloc * lda + kt * 32 + cs * 8;
    else src = Bbase + (size_t)(rloc - BM) * ldb + kt * 32 + cs * 8;
    gload16(src, &ring[slot][u * 512]);
  };

  f32x4 acc[8][4];
  const f32x4 zero = {0.f, 0.f, 0.f, 0.f};
#pragma unroll
  for (int m = 0; m < 8; ++m)
#pragma unroll
    for (int n = 0; n < 4; ++n) acc[m][n] = zero;

  const int NT = K >> 5;
#pragma unroll
  for (int s = 0; s < 3; ++s)
#pragma unroll
    for (int j = 0; j < 4; ++j) stage1(s, s, j);
  vmcw<8>();
  __builtin_amdgcn_s_barrier(); SB0;

  const int co = ((hi ^ ((lr >> 1) & 3)) * 8);
  int sl = 0, st = DEPTH;
  for (int k = 0; k < NT; ++k) {
    const u16* la = &ring[sl][0];
    const u16* lb = &ring[sl][BM * 32];
    const bool do_stage = (k + DEPTH) < NT;
    short8 bf[4];
#pragma unroll
    for (int q = 0; q < 4; ++q) {
      short8 af0 = *(const short8*)(la + (wr * 128 + (2 * q) * 16 + lr) * 32 + co);
      short8 af1 = *(const short8*)(la + (wr * 128 + (2 * q + 1) * 16 + lr) * 32 + co);
      if (q == 0) {
#pragma unroll
        for (int n = 0; n < 4; ++n)
          bf[n] = *(const short8*)(lb + (wc * 64 + n * 16 + lr) * 32 + co);
      }
      if (do_stage) stage1(st, k + DEPTH, q);
      __builtin_amdgcn_s_barrier(); SB0;
      lgkm0();
      __builtin_amdgcn_s_setprio(1);
#pragma unroll
      for (int n = 0; n < 4; ++n)
        acc[2 * q][n] = __builtin_amdgcn_mfma_f32_16x16x32_bf16(af0, bf[n], acc[2 * q][n], 0, 0, 0);
#pragma unroll
      for (int n = 0; n < 4; ++n)
        acc[2 * q + 1][n] = __builtin_amdgcn_mfma_f32_16x16x32_bf16(af1, bf[n], acc[2 * q + 1][n], 0, 0, 0);
      __builtin_amdgcn_s_setprio(0);
      if (q == 3) {
        if (k + RING < NT) vmcw<8>();
        else if (k + 1 < NT) vmcw<0>();
      }
      __builtin_amdgcn_s_barrier(); SB0;
    }
    sl = (sl + 1) & 3;
    st = (st + 1) & 3;
  }

#pragma unroll
  for (int m = 0; m < 8; ++m) {
    int row0 = rb * BM + wr * 128 + m * 16 + hi * 4;
#pragma unroll
    for (int n = 0; n < 4; ++n) {
      int col = cb * BM + wc * 64 + n * 16 + lr;
      float sc = (col < split) ? scale : 1.0f;
      float bv = 0.0f;
      if (z == 0) bv = (col < split) ? bias[col] : bias2[col - split];
#pragma unroll
      for (int r = 0; r < 4; ++r) {
        float v = (acc[m][n][r] + bv) * sc;
        if (RELU) v = fmaxf(v, 0.0f);
        if constexpr (sizeof(OutT) == 2)
          C[(size_t)(row0 + r) * ldc + col] = f2bf(v);
        else
          C[(size_t)(row0 + r) * ldc + col] = v;
      }
    }
  }
}

// ---------- 128x128 ring-4 GEMM (R5-proven; out-proj only) ----------
template <typename OutT, bool RELU>
__global__ __launch_bounds__(256, 2) void gemm_ring_kernel(
    const u16* __restrict__ A, int lda,
    const u16* __restrict__ Bt, int ldb,
    const float* __restrict__ bias, const float* __restrict__ bias2, int split,
    OutT* __restrict__ C, int ldc, size_t c_off, int K, float scale) {
  constexpr int BM = 128, RING = 4, DEPTH = 3;
  constexpr int SLOT = 256 * 32;
  __shared__ __align__(16) u16 ring[RING][SLOT];

  const int tid = threadIdx.x;
  const int lane = tid & 63, wid = tid >> 6;
  const int wr = wid >> 1, wc = wid & 1;
  const int lr = lane & 15, hi = lane >> 4;
  const int z = blockIdx.z;

  const int gx = gridDim.x;
  const int nwg = gx * gridDim.y;
  const int orig = blockIdx.y * gx + blockIdx.x;
  const int q8 = nwg >> 3, r8 = nwg & 7, xcd = orig & 7, oo = orig >> 3;
  const int lid = (xcd < r8 ? xcd * (q8 + 1) : r8 * (q8 + 1) + (xcd - r8) * q8) + oo;
  const int rb = lid / gx, cb = lid % gx;

  const u16* Abase = A + (size_t)rb * BM * lda + (size_t)z * K;
  const u16* Bbase = Bt + (size_t)cb * BM * ldb + (size_t)z * K;
  C += (size_t)z * c_off;

  auto stage = [&](int slot, int kt) {
#pragma unroll
    for (int j = 0; j < 4; ++j) {
      int u = wid * 4 + j;
      int rloc = u * 16 + (lane >> 2);
      int cs = (lane & 3) ^ ((rloc >> 1) & 3);
      const u16* src;
      if (u < 8) src = Abase + (size_t)rloc * lda + kt * 32 + cs * 8;
      else src = Bbase + (size_t)(rloc - BM) * ldb + kt * 32 + cs * 8;
      gload16(src, &ring[slot][u * 512]);
    }
  };

  f32x4 acc[4][4];
  const f32x4 zero = {0.f, 0.f, 0.f, 0.f};
#pragma unroll
  for (int m = 0; m < 4; ++m)
#pragma unroll
    for (int n = 0; n < 4; ++n) acc[m][n] = zero;

  const int NT = K >> 5;
  stage(0, 0); stage(1, 1); stage(2, 2);
  vmcw<8>();
  __builtin_amdgcn_s_barrier(); SB0;

  const int sw = (lr >> 1) & 3;
  int sl = 0, st = DEPTH;
  for (int k = 0; k < NT; ++k) {
    const u16* la = &ring[sl][0];
    const u16* lb = &ring[sl][BM * 32];
    short8 bf[4], af[4];
#pragma unroll
    for (int n = 0; n < 4; ++n)
      bf[n] = *(const short8*)(lb + (wc * 64 + n * 16 + lr) * 32 + ((hi ^ sw) * 8));
#pragma unroll
    for (int m = 0; m < 4; ++m)
      af[m] = *(const short8*)(la + (wr * 64 + m * 16 + lr) * 32 + ((hi ^ sw) * 8));
    if (k + DEPTH < NT) stage(st, k + DEPTH);
    __builtin_amdgcn_s_setprio(1);
#pragma unroll
    for (int m = 0; m < 4; ++m)
#pragma unroll
      for (int n = 0; n < 4; ++n)
        acc[m][n] = __builtin_amdgcn_mfma_f32_16x16x32_bf16(af[m], bf[n], acc[m][n], 0, 0, 0);
    __builtin_amdgcn_s_setprio(0);
    if (k + RING < NT) vmcw<8>();
    else if (k + 1 < NT) vmcw<0>();
    __builtin_amdgcn_s_barrier(); SB0;
    sl = (sl + 1) & 3;
    st = (st + 1) & 3;
  }

#pragma unroll
  for (int m = 0; m < 4; ++m) {
    int row0 = rb * BM + wr * 64 + m * 16 + hi * 4;
#pragma unroll
    for (int n = 0; n < 4; ++n) {
      int col = cb * BM + wc * 64 + n * 16 + lr;
      float sc = (col < split) ? scale : 1.0f;
      float bv = 0.0f;
      if (z == 0) bv = (col < split) ? bias[col] : bias2[col - split];
#pragma unroll
      for (int r = 0; r < 4; ++r) {
        float v = (acc[m][n][r] + bv) * sc;
        if (RELU) v = fmaxf(v, 0.0f);
        if constexpr (sizeof(OutT) == 2)
          C[(size_t)(row0 + r) * ldc + col] = f2bf(v);
        else
          C[(size_t)(row0 + r) * ldc + col] = v;
      }
    }
  }
}

// ---------- fused flash attention (unchanged from R5) ----------
__global__ __launch_bounds__(512, 2) void attn_kernel(
    const u16* __restrict__ QKV, const u16* __restrict__ Vtp,
    const int* __restrict__ mask, u16* __restrict__ CTX) {
  __shared__ __align__(16) u16 kl[2][64 * 64];
  __shared__ __align__(16) u16 vl[2][64 * 64];
  __shared__ unsigned long long mask_lds[16];
  const int lane = threadIdx.x & 63;
  const int wid = threadIdx.x >> 6;
  const int lr = lane & 15, hi = lane >> 4;
  const int bh = blockIdx.x, qt = blockIdx.y;
  const int b = bh >> 4, h = bh & 15;

  const size_t qrow = (size_t)(b * 1024 + qt * 128 + wid * 16 + lr);
  short8 qf[2];
#pragma unroll
  for (int ks = 0; ks < 2; ++ks)
    qf[ks] = *(const short8*)(QKV + qrow * 3072 + h * 64 + ks * 32 + hi * 8);

#pragma unroll
  for (int i = 0; i < 2; ++i) {
    int kt = wid * 2 + i;
    unsigned long long bal = __ballot(mask[b * 1024 + kt * 64 + lane] != 0);
    if (lane == 0) mask_lds[kt] = bal;
  }

  const u16* Kbase = QKV + (size_t)(b * 1024) * 3072 + 1024 + h * 64;
  const u16* Vbase = Vtp + (size_t)(h * 64) * 4096 + b * 1024;

  auto stage = [&](int bf, int kt) {
    int r = wid * 8 + (lane >> 3);
    int cs = (lane & 7) ^ (r & 7);
    gload16(Kbase + (size_t)(kt * 64 + r) * 3072 + cs * 8, &kl[bf][wid * 8 * 64]);
    gload16(Vbase + (size_t)r * 4096 + kt * 64 + cs * 8, &vl[bf][wid * 8 * 64]);
  };

  float m_run = -3.0e38f, l_run = 0.0f;
  f32x4 O[4];
  const f32x4 zero = {0.f, 0.f, 0.f, 0.f};
#pragma unroll
  for (int d = 0; d < 4; ++d) O[d] = zero;

  stage(0, 0);
  __syncthreads();
  int cur = 0;
  for (int kt = 0; kt < 16; ++kt) {
    if (kt + 1 < 16) stage(cur ^ 1, kt + 1);

    f32x4 s[4];
#pragma unroll
    for (int n = 0; n < 4; ++n) s[n] = zero;
    __builtin_amdgcn_s_setprio(1);
#pragma unroll
    for (int n = 0; n < 4; ++n) {
      int key = n * 16 + lr;
#pragma unroll
      for (int ks = 0; ks < 2; ++ks) {
        int ch = (hi + 4 * ks) ^ (key & 7);
        short8 kf = *(const short8*)(kl[cur] + key * 64 + ch * 8);
        s[n] = __builtin_amdgcn_mfma_f32_16x16x32_bf16(kf, qf[ks], s[n], 0, 0, 0);
      }
    }
    __builtin_amdgcn_s_setprio(0);

    unsigned long long mk = mask_lds[kt];
    if (mk != ~0ull) {
#pragma unroll
      for (int n = 0; n < 4; ++n)
#pragma unroll
        for (int r = 0; r < 4; ++r)
          if (!((mk >> (n * 16 + hi * 4 + r)) & 1ull)) s[n][r] = -3.0e38f;
    }

    float tm = -3.0e38f;
#pragma unroll
    for (int n = 0; n < 4; ++n)
      tm = fmaxf(tm, fmaxf(fmaxf(s[n][0], s[n][1]), fmaxf(s[n][2], s[n][3])));
    tm = fmaxf(tm, __shfl_xor(tm, 16));
    tm = fmaxf(tm, __shfl_xor(tm, 32));

    float mo = m_run;
    bool grow = __any(tm > mo);
    float mn = grow ? fmaxf(mo, tm) : mo;
    m_run = mn;
    float ps = 0.0f;
#pragma unroll
    for (int n = 0; n < 4; ++n)
#pragma unroll
      for (int r = 0; r < 4; ++r) {
        float p = __expf(s[n][r] - mn);
        s[n][r] = p;
        ps += p;
      }
    if (grow) {
      float alpha = __expf(mo - mn);
      l_run = l_run * alpha + ps;
#pragma unroll
      for (int d = 0; d < 4; ++d)
#pragma unroll
        for (int r = 0; r < 4; ++r) O[d][r] *= alpha;
    } else {
      l_run += ps;
    }

#pragma unroll
    for (int ks = 0; ks < 2; ++ks) {
      union { unsigned u[4]; short8 s8; } pf;
      pf.u[0] = cvtpk(s[2 * ks][0], s[2 * ks][1]);
      pf.u[1] = cvtpk(s[2 * ks][2], s[2 * ks][3]);
      pf.u[2] = cvtpk(s[2 * ks + 1][0], s[2 * ks + 1][1]);
      pf.u[3] = cvtpk(s[2 * ks + 1][2], s[2 * ks + 1][3]);
      __builtin_amdgcn_s_setprio(1);
#pragma unroll
      for (int d = 0; d < 4; ++d) {
        int vrow = d * 16 + lr;
        int ch = (hi + 4 * ks) ^ (vrow & 7);
        short8 vf = *(const short8*)(vl[cur] + vrow * 64 + ch * 8);
        O[d] = __builtin_amdgcn_mfma_f32_16x16x32_bf16(vf, pf.s8, O[d], 0, 0, 0);
      }
      __builtin_amdgcn_s_setprio(0);
    }
    __syncthreads();
    cur ^= 1;
  }

  float l = l_run;
  l += __shfl_xor(l, 16);
  l += __shfl_xor(l, 32);
  float inv = 1.0f / l;
#pragma unroll
  for (int dt = 0; dt < 4; ++dt) {
    uint2 w;
    w.x = cvtpk(O[dt][0] * inv, O[dt][1] * inv);
    w.y = cvtpk(O[dt][2] * inv, O[dt][3] * inv);
    *(uint2*)(CTX + qrow * 1024 + h * 64 + dt * 16 + hi * 4) = w;
  }
}

// ---------- allennlp LayerNorm of (xa+xb) -> fp32 + bf16 ----------
__global__ __launch_bounds__(256) void ln_kernel(
    const float* __restrict__ xa, const float* __restrict__ xb,
    const float* __restrict__ g, const float* __restrict__ beta,
    float* __restrict__ of, u16* __restrict__ ob) {
  int row = blockIdx.x;
  int tid = threadIdx.x;
  const float* pa = xa + (size_t)row * 1024;
  const float* pb = xb + (size_t)row * 1024;
  float v[4];
  float s = 0.f, s2 = 0.f;
#pragma unroll
  for (int j = 0; j < 4; ++j) {
    int c = tid + j * 256;
    float x = pa[c] + pb[c];
    v[j] = x; s += x; s2 += x * x;
  }
#pragma unroll
  for (int d = 1; d < 64; d <<= 1) {
    s += __shfl_xor(s, d);
    s2 += __shfl_xor(s2, d);
  }
  __shared__ float red[8];
  int w = tid >> 6, lane = tid & 63;
  if (lane == 0) { red[w] = s; red[4 + w] = s2; }
  __syncthreads();
  s = red[0] + red[1] + red[2] + red[3];
  s2 = red[4] + red[5] + red[6] + red[7];
  float mean = s * (1.0f / 1024.0f);
  float var = fmaxf((s2 - 1024.0f * mean * mean) * (1.0f / 1023.0f), 0.0f);
  float rden = 1.0f / (sqrtf(var) + 1e-6f);
#pragma unroll
  for (int j = 0; j < 4; ++j) {
    int c = tid + j * 256;
    float y = g[c] * (v[j] - mean) * rden + beta[c];
    of[(size_t)row * 1024 + c] = y;
    if (ob) ob[(size_t)row * 1024 + c] = f2bf(y);
  }
}

// ---------- LN2: LN(x1 + sum of 4 bf16 partials) -> fp32 out ----------
__global__ __launch_bounds__(256) void ln2p_kernel(
    const float* __restrict__ x1, const u16* __restrict__ p, size_t pstride,
    const float* __restrict__ g, const float* __restrict__ beta,
    float* __restrict__ out) {
  int row = blockIdx.x;
  int tid = threadIdx.x;
  int c0 = tid * 4;
  float4 v4 = *reinterpret_cast<const float4*>(x1 + (size_t)row * 1024 + c0);
  float v[4] = {v4.x, v4.y, v4.z, v4.w};
#pragma unroll
  for (int i = 0; i < 4; ++i) {
    ushort4 u4 = *reinterpret_cast<const ushort4*>(p + i * pstride + (size_t)row * 1024 + c0);
    v[0] += bf2f(u4.x); v[1] += bf2f(u4.y); v[2] += bf2f(u4.z); v[3] += bf2f(u4.w);
  }
  float s = 0.f, s2 = 0.f;
#pragma unroll
  for (int j = 0; j < 4; ++j) { s += v[j]; s2 += v[j] * v[j]; }
#pragma unroll
  for (int d = 1; d < 64; d <<= 1) {
    s += __shfl_xor(s, d);
    s2 += __shfl_xor(s2, d);
  }
  __shared__ float red[8];
  int w = tid >> 6, lane = tid & 63;
  if (lane == 0) { red[w] = s; red[4 + w] = s2; }
  __syncthreads();
  s = red[0] + red[1] + red[2] + red[3];
  s2 = red[4] + red[5] + red[6] + red[7];
  float mean = s * (1.0f / 1024.0f);
  float var = fmaxf((s2 - 1024.0f * mean * mean) * (1.0f / 1023.0f), 0.0f);
  float rden = 1.0f / (sqrtf(var) + 1e-6f);
  float4 o;
  o.x = g[c0 + 0] * (v[0] - mean) * rden + beta[c0 + 0];
  o.y = g[c0 + 1] * (v[1] - mean) * rden + beta[c0 + 1];
  o.z = g[c0 + 2] * (v[2] - mean) * rden + beta[c0 + 2];
  o.w = g[c0 + 3] * (v[3] - mean) * rden + beta[c0 + 3];
  *reinterpret_cast<float4*>(out + (size_t)row * 1024 + c0) = o;
}

extern "C" void kernel_launch(void* const* d_in, const int* in_sizes, int n_in,
                              void* d_out, int out_size, void* d_ws, size_t ws_size,
                              hipStream_t stream) {
  const float* src   = (const float*)d_in[0];
  const int*   mask  = (const int*)d_in[1];
  const float* q_w   = (const float*)d_in[2];
  const float* q_b   = (const float*)d_in[3];
  const float* kv_w  = (const float*)d_in[4];
  const float* kv_b  = (const float*)d_in[5];
  const float* out_w = (const float*)d_in[6];
  const float* out_b = (const float*)d_in[7];
  const float* w1    = (const float*)d_in[8];
  const float* b1    = (const float*)d_in[9];
  const float* w2    = (const float*)d_in[10];
  const float* b2    = (const float*)d_in[11];
  const float* g1    = (const float*)d_in[12];
  const float* be1   = (const float*)d_in[13];
  const float* g2    = (const float*)d_in[14];
  const float* be2   = (const float*)d_in[15];
  float* out = (float*)d_out;

  char* ws = (char*)d_ws;
  const size_t MB = 1024 * 1024;
  const int BIG = 1 << 30;
  u16*  Xbf   = (u16*)(ws + 0);          //  8MB, dead after QKV
  u16*  CTX   = (u16*)(ws + 8 * MB);     //  8MB, dead after out-proj
  u16*  WqkvT = (u16*)(ws + 16 * MB);    //  6MB, dead after QKV
  u16*  WoT   = (u16*)(ws + 22 * MB);    //  2MB, dead after out-proj
  u16*  W1T   = (u16*)(ws + 24 * MB);    //  8MB
  u16*  W2T   = (u16*)(ws + 32 * MB);    //  8MB
  u16*  QKV   = (u16*)(ws + 40 * MB);    // 24MB, dead after attn
  u16*  Vtp   = (u16*)(ws + 64 * MB);    //  8MB, dead after attn
  u16*  F1b   = (u16*)(ws + 40 * MB);    // 32MB, aliases QKV+Vtp
  float* AOUT = (float*)(ws + 72 * MB);  // 16MB, dead after LN1
  float* OUT1F= (float*)(ws + 88 * MB);  // 16MB
  u16*  OUT1B = (u16*)(ws + 104 * MB);   //  8MB, dead after FFN1
  u16*  FP    = (u16*)(ws + 0);          // 32MB: 4 bf16 partials (aliases 0-32, dead by FFN2)

  // 1. prep
  prep_kernel<<<dim3(16384), dim3(256), 0, stream>>>(
      src, q_w, kv_w, out_w, w1, w2, Xbf, WqkvT, WoT, W1T, W2T);
  // 2. QKV (4-phase 256²): grid 12x16, K=1024
  gemm_4ph_kernel<u16, false><<<dim3(12, 16), dim3(512), 0, stream>>>(
      Xbf, 1024, WqkvT, 1024, q_b, kv_b, 1024, QKV, 3072, 0, 1024, 0.125f);
  // 3. Vtp
  transpose_vtp_kernel<<<dim3(32, 128), dim3(32, 8), 0, stream>>>(QKV, Vtp);
  // 4. attention
  attn_kernel<<<dim3(64, 8), dim3(512), 0, stream>>>(QKV, Vtp, mask, CTX);
  // 5. out-proj (128² ring)
  gemm_ring_kernel<float, false><<<dim3(8, 32), dim3(256), 0, stream>>>(
      CTX, 1024, WoT, 1024, out_b, nullptr, BIG, AOUT, 1024, 0, 1024, 1.0f);
  // 6. LN1
  ln_kernel<<<dim3(4096), dim3(256), 0, stream>>>(src, AOUT, g1, be1, OUT1F, OUT1B);
  // 7. FFN1 (4-phase 256²): grid 16x16, K=1024
  gemm_4ph_kernel<u16, true><<<dim3(16, 16), dim3(512), 0, stream>>>(
      OUT1B, 1024, W1T, 1024, b1, nullptr, BIG, F1b, 4096, 0, 1024, 1.0f);
  // 8. FFN2 (4-phase 256², splitK=4 -> 256 blocks, bf16 partials at ws+0)
  gemm_4ph_kernel<u16, false><<<dim3(4, 16, 4), dim3(512), 0, stream>>>(
      F1b, 4096, W2T, 4096, b2, nullptr, BIG, FP, 1024,
      (size_t)(4 * MB), 1024, 1.0f);
  // 9. LN2 = LN(out1 + sum of 4 partials)
  ln2p_kernel<<<dim3(4096), dim3(256), 0, stream>>>(
      OUT1F, FP, 4 * MB, g2, be2, out);
  (void)in_sizes; (void)n_in; (void)out_size; (void)ws_size;
}